// Round 1
// baseline (888.262 us; speedup 1.0000x reference)
//
#include <hip/hip_runtime.h>

typedef __attribute__((ext_vector_type(4))) float f32x4;

#define T_TOK 16384
#define D_DIM 4096
#define E_EXP 64
#define KST    128              // k-extent per LDS stage
#define NSTAGE (D_DIM / KST)    // 32
#define TPW    8                // tokens per wave
#define NWAVE  4
#define THREADS (NWAVE * 64)    // 256
#define TOKPB  (NWAVE * TPW)    // 32
#define NBLK   (T_TOK / TOKPB)  // 512 blocks -> 2 per CU (64 KB LDS each)

typedef __attribute__((address_space(3))) uint32_t lds_u32;
typedef const __attribute__((address_space(1))) uint32_t glb_u32;

// One fused kernel. lane = expert; wave owns TPW tokens; acc in VGPRs.
// eg staged in double-buffered LDS via global_load_lds (linear dest) with the
// XOR swizzle applied to the per-lane GLOBAL source address; reads apply the
// same XOR -> ds_read_b128 row-read is bank-uniform (8 words/bank = minimal).
// th rows are wave-uniform (readfirstlane on wave id) -> scalar s_load path,
// so the inner loop is v_fmac_f32 acc, s_th, v_eg on the VALU pipe only.
__global__ __launch_bounds__(THREADS, 2)
void moe_fused_kernel(const float* __restrict__ th, const float* __restrict__ eg,
                      const float* __restrict__ rl, const float* __restrict__ alpha_p,
                      float* __restrict__ out) {
  __shared__ __align__(16) float lds_eg[2][E_EXP * KST];   // 2 x 32 KB

  const int tid  = threadIdx.x;
  const int lane = tid & 63;
  const int wu   = __builtin_amdgcn_readfirstlane(tid >> 6);  // uniform wave id
  const int l7   = lane & 7;
  const int tokbase = blockIdx.x * TOKPB + wu * TPW;
  const float alpha = alpha_p[0];

  // Wave-uniform token row pointers (scalar loads in the hot loop).
  const float* trow[TPW];
#pragma unroll
  for (int t = 0; t < TPW; ++t)
    trow[t] = th + (size_t)(tokbase + t) * D_DIM;

  float acc[TPW];
#pragma unroll
  for (int t = 0; t < TPW; ++t) acc[t] = 0.f;

  // ---- stage 0 ----
  {
#pragma unroll
    for (int it = 0; it < 8; ++it) {
      int r0 = (wu * 8 + it) * 2;          // two expert rows per issue
      int e  = r0 + (lane >> 5);
      int L  = lane & 31;
      const float* gp = eg + (size_t)e * D_DIM + ((L ^ (e & 7)) << 2);
      __builtin_amdgcn_global_load_lds((glb_u32*)gp,
                                       (lds_u32*)&lds_eg[0][r0 * KST], 16, 0, 0);
    }
  }
  __syncthreads();

  for (int s = 0; s < NSTAGE; ++s) {
    const int buf = s & 1;
    // Issue next stage into the other buffer; loads complete during compute,
    // the barrier's vmcnt(0) drain at the end costs ~nothing.
    if (s + 1 < NSTAGE) {
      const int k0n = (s + 1) * KST;
#pragma unroll
      for (int it = 0; it < 8; ++it) {
        int r0 = (wu * 8 + it) * 2;
        int e  = r0 + (lane >> 5);
        int L  = lane & 31;
        const float* gp = eg + (size_t)e * D_DIM + k0n + ((L ^ (e & 7)) << 2);
        __builtin_amdgcn_global_load_lds((glb_u32*)gp,
                                         (lds_u32*)&lds_eg[buf ^ 1][r0 * KST], 16, 0, 0);
      }
    }

    const int k0 = s * KST;
    const float* lbase = &lds_eg[buf][lane * KST];   // this lane's expert row
#pragma unroll 2
    for (int jb = 0; jb < KST / 16; ++jb) {          // 8 iterations
      f32x4 ev[4];
#pragma unroll
      for (int q = 0; q < 4; ++q) {
        int qq = jb * 4 + q;                         // 16B block index in row
        ev[q] = *(const f32x4*)(lbase + ((qq ^ l7) << 2));  // de-swizzled read
      }
#pragma unroll
      for (int t = 0; t < TPW; ++t) {
        const float* tr = trow[t] + k0 + jb * 16;    // uniform -> s_load_dwordx4
#pragma unroll
        for (int q = 0; q < 4; ++q) {
          f32x4 a = *(const f32x4*)(tr + q * 4);
          acc[t] = fmaf(a[0], ev[q][0], acc[t]);
          acc[t] = fmaf(a[1], ev[q][1], acc[t]);
          acc[t] = fmaf(a[2], ev[q][2], acc[t]);
          acc[t] = fmaf(a[3], ev[q][3], acc[t]);
        }
      }
    }
    __syncthreads();
  }

  // ---- epilogue: exact fp32 top-2 + softmax-of-2, in-wave ----
#pragma unroll 1
  for (int t = 0; t < TPW; ++t) {
    const int tok = tokbase + t;
    float g = rl[(size_t)tok * E_EXP + lane] + alpha * acc[t];

    float v1 = g; int i1 = lane;
#pragma unroll
    for (int off = 32; off > 0; off >>= 1) {
      float vo = __shfl_down(v1, off, 64);
      int   io = __shfl_down(i1, off, 64);
      if (vo > v1 || (vo == v1 && io < i1)) { v1 = vo; i1 = io; }
    }
    v1 = __shfl(v1, 0, 64); i1 = __shfl(i1, 0, 64);

    float g2 = (lane == i1) ? -3.4e38f : g;
    float v2 = g2; int i2 = lane;
#pragma unroll
    for (int off = 32; off > 0; off >>= 1) {
      float vo = __shfl_down(v2, off, 64);
      int   io = __shfl_down(i2, off, 64);
      if (vo > v2 || (vo == v2 && io < i2)) { v2 = vo; i2 = io; }
    }

    if (lane == 0) {
      float ew  = __expf(v2 - v1);
      float inv = 1.f / (1.f + ew);
      ((float4*)out)[tok] = make_float4((float)i1, inv, (float)i2, ew * inv);
    }
  }
}

extern "C" void kernel_launch(void* const* d_in, const int* in_sizes, int n_in,
                              void* d_out, int out_size, void* d_ws, size_t ws_size,
                              hipStream_t stream) {
  const float* th      = (const float*)d_in[0];  // [T, D]
  const float* rl      = (const float*)d_in[1];  // [T, E]
  const float* eg      = (const float*)d_in[2];  // [E, D]
  const float* alpha_p = (const float*)d_in[3];  // scalar
  float* out = (float*)d_out;                    // [T, 2, 2]
  (void)d_ws; (void)ws_size;

  moe_fused_kernel<<<NBLK, THREADS, 0, stream>>>(th, eg, rl, alpha_p, out);
}

// Round 2
// 432.929 us; speedup vs baseline: 2.0518x; 2.0518x over previous
//
#include <hip/hip_runtime.h>

typedef __attribute__((ext_vector_type(4))) float f32x4;
typedef __attribute__((ext_vector_type(8))) short short8;

#define T_TOK 16384
#define D_DIM 4096
#define E_EXP 64
#define BKC 128
#define NCHUNK (D_DIM / BKC)   // 32
#define GAP_THR 0.1f
#define LIST_CAP 8192

typedef __attribute__((address_space(3))) uint32_t lds_u32;
typedef const __attribute__((address_space(1))) uint32_t glb_u32;

// fp32 -> bf16 hi (truncate) + bf16 lo (truncate of exact residual).
__device__ __forceinline__ void cvt8(const f32x4& x, const f32x4& y,
                                     short8& hi, short8& lo) {
  float v[8] = {x[0], x[1], x[2], x[3], y[0], y[1], y[2], y[3]};
#pragma unroll
  for (int j = 0; j < 8; ++j) {
    unsigned b = __float_as_uint(v[j]);
    hi[j] = (short)(b >> 16);
    float l = v[j] - __uint_as_float(b & 0xffff0000u);
    lo[j] = (short)(__float_as_uint(l) >> 16);
  }
}

// Pre-convert eg [64 x 4096] fp32 -> bf16 hi/lo fragments laid out so that
// global_load_lds (lane-linear dest) lands exactly in MFMA fragment order.
// Unit u = ((c*2+p)*16 + s)*64 + l : 16 bytes = 8 bf16, expert n=(s&3)*16+(l&15),
// k = c*128 + (s>>2)*32 + (l>>4)*8. Also zeroes the fix-list counter.
__global__ __launch_bounds__(256)
void moe_precvt_kernel(const float* __restrict__ eg, short* __restrict__ egb,
                       int* __restrict__ cnt) {
  if (blockIdx.x == 0 && threadIdx.x == 0) *cnt = 0;
  int u = blockIdx.x * 256 + threadIdx.x;     // 65536 units
  int l = u & 63, s = (u >> 6) & 15, p = (u >> 10) & 1, c = u >> 11;
  int n = (s & 3) * 16 + (l & 15);
  int k = c * BKC + (s >> 2) * 32 + (l >> 4) * 8;
  const float* src = eg + (size_t)n * D_DIM + k;
  f32x4 x = *(const f32x4*)src;
  f32x4 y = *(const f32x4*)(src + 4);
  short8 hi, lo;
  cvt8(x, y, hi, lo);
  *(short8*)&egb[(size_t)u * 8] = (p == 0) ? hi : lo;
}

// Fused GEMM + top-2. Block: 32 tokens x 64 experts, 4 waves
// (wm = token-group of 16, wn = expert-half of 32). B staged bf16 via
// global_load_lds (no conversion in hot loop), double-buffered; A prefetched
// one chunk ahead into registers, converted on the fly (once per element).
__global__ __launch_bounds__(256, 2)
void moe_main_kernel(const float* __restrict__ th, const short* __restrict__ egb,
                     const float* __restrict__ rl, const float* __restrict__ alpha_p,
                     float* __restrict__ out, int* __restrict__ cnt,
                     int* __restrict__ list) {
  __shared__ __align__(16) short lds[2][16384];   // 2 x 32 KB
  const int tid  = threadIdx.x;
  const int lane = tid & 63;
  const int wu   = __builtin_amdgcn_readfirstlane(tid >> 6);
  const int wm   = wu >> 1, wn = wu & 1;
  const int m    = lane & 15, quad = lane >> 4;
  const int tb   = blockIdx.x;

  const int tok = tb * 32 + wm * 16 + m;
  const float* aptr = th + (size_t)tok * D_DIM + quad * 8;

  f32x4 acc[2];
  acc[0] = (f32x4){0.f, 0.f, 0.f, 0.f};
  acc[1] = (f32x4){0.f, 0.f, 0.f, 0.f};

  // Stage one B chunk (32 slots x 1KB): wave wu issues 8 global_load_lds.
  auto stage = [&](int c, int buf) {
#pragma unroll
    for (int it = 0; it < 8; ++it) {
      int idx = wu * 8 + it;                      // 0..31 (p = idx>>4, s = idx&15)
      const short* gp = egb + ((size_t)c * 2048 + (size_t)idx * 64 + lane) * 8;
      __builtin_amdgcn_global_load_lds((glb_u32*)gp,
                                       (lds_u32*)&lds[buf][idx * 512], 16, 0, 0);
    }
  };

  auto loadA = [&](f32x4* pa, int c) {
    const float* ap = aptr + c * BKC;
#pragma unroll
    for (int ks = 0; ks < 4; ++ks) {
      pa[2 * ks]     = *(const f32x4*)(ap + ks * 32);
      pa[2 * ks + 1] = *(const f32x4*)(ap + ks * 32 + 4);
    }
  };

  auto computeC = [&](int buf, const f32x4* pa) {
#pragma unroll
    for (int ks = 0; ks < 4; ++ks) {
      short8 ahi, alo;
      cvt8(pa[2 * ks], pa[2 * ks + 1], ahi, alo);
#pragma unroll
      for (int nt = 0; nt < 2; ++nt) {
        int s = ks * 4 + wn * 2 + nt;
        short8 bhi = *(const short8*)&lds[buf][s * 512 + lane * 8];
        short8 blo = *(const short8*)&lds[buf][8192 + s * 512 + lane * 8];
        acc[nt] = __builtin_amdgcn_mfma_f32_16x16x32_bf16(ahi, bhi, acc[nt], 0, 0, 0);
        acc[nt] = __builtin_amdgcn_mfma_f32_16x16x32_bf16(ahi, blo, acc[nt], 0, 0, 0);
        acc[nt] = __builtin_amdgcn_mfma_f32_16x16x32_bf16(alo, bhi, acc[nt], 0, 0, 0);
      }
    }
  };

  f32x4 paA[8], paB[8];
  stage(0, 0);
  loadA(paA, 0);
  __syncthreads();                                // chunk 0 staged
#pragma unroll 1
  for (int c = 0; c < NCHUNK; c += 2) {
    stage(c + 1, 1);
    loadA(paB, c + 1);
    computeC(0, paA);
    __syncthreads();                              // chunk c+1 staged; buf0 free
    if (c + 2 < NCHUNK) { stage(c + 2, 0); loadA(paA, c + 2); }
    computeC(1, paB);
    __syncthreads();                              // chunk c+2 staged; buf1 free
  }

  // Epilogue: dots -> LDS, then wave-per-8-tokens top-2 + softmax-of-2.
  float* g = (float*)&lds[0][0];                  // [32][64]
#pragma unroll
  for (int nt = 0; nt < 2; ++nt)
#pragma unroll
    for (int i = 0; i < 4; ++i)
      g[(wm * 16 + quad * 4 + i) * 64 + wn * 32 + nt * 16 + m] = acc[nt][i];
  __syncthreads();

  const float alpha = alpha_p[0];
#pragma unroll 1
  for (int tt = 0; tt < 8; ++tt) {
    int tl   = wu * 8 + tt;
    int tokg = tb * 32 + tl;
    float gv = rl[(size_t)tokg * E_EXP + lane] + alpha * g[tl * 64 + lane];

    float v1 = gv; int i1 = lane;
#pragma unroll
    for (int off = 32; off > 0; off >>= 1) {
      float vo = __shfl_down(v1, off, 64);
      int   io = __shfl_down(i1, off, 64);
      if (vo > v1 || (vo == v1 && io < i1)) { v1 = vo; i1 = io; }
    }
    v1 = __shfl(v1, 0, 64); i1 = __shfl(i1, 0, 64);

    float g2 = (lane == i1) ? -3.4e38f : gv;
    float v2 = g2; int i2 = lane;
#pragma unroll
    for (int off = 32; off > 0; off >>= 1) {
      float vo = __shfl_down(v2, off, 64);
      int   io = __shfl_down(i2, off, 64);
      if (vo > v2 || (vo == v2 && io < i2)) { v2 = vo; i2 = io; }
    }

    if (lane == 0) {
      float ew  = __expf(v2 - v1);
      float inv = 1.f / (1.f + ew);
      ((float4*)out)[tokg] = make_float4((float)i1, inv, (float)i2, ew * inv);
      if (v1 - v2 < GAP_THR) {
        int idx = atomicAdd(cnt, 1);
        if (idx < LIST_CAP) list[idx] = tokg;
      }
    }
  }
}

// Exact fp32 recompute of flagged tokens (4 waves split k, lane=expert).
__global__ __launch_bounds__(256)
void moe_fix_kernel(const float* __restrict__ th, const float* __restrict__ eg,
                    const float* __restrict__ rl, const float* __restrict__ alpha_p,
                    float* __restrict__ out, const int* __restrict__ cnt,
                    const int* __restrict__ list) {
  __shared__ float lds_p[4][64];
  const int wave = threadIdx.x >> 6, lane = threadIdx.x & 63;
  const float alpha = alpha_p[0];
  int count = *cnt;
  if (count > LIST_CAP) count = LIST_CAP;

  for (int i = blockIdx.x; i < count; i += gridDim.x) {
    int t = list[i];
    const float* tr = th + (size_t)t * D_DIM + wave * 1024;
    const float* er = eg + (size_t)lane * D_DIM + wave * 1024;
    float d = 0.f;
    for (int k = 0; k < 1024; k += 4) {
      float4 a = *(const float4*)(tr + k);
      float4 b = *(const float4*)(er + k);
      d = fmaf(a.x, b.x, d); d = fmaf(a.y, b.y, d);
      d = fmaf(a.z, b.z, d); d = fmaf(a.w, b.w, d);
    }
    lds_p[wave][lane] = d;
    __syncthreads();
    if (wave == 0) {
      float dot = lds_p[0][lane] + lds_p[1][lane] + lds_p[2][lane] + lds_p[3][lane];
      float g = rl[(size_t)t * E_EXP + lane] + alpha * dot;
      float v1 = g; int i1 = lane;
#pragma unroll
      for (int off = 32; off > 0; off >>= 1) {
        float vo = __shfl_down(v1, off, 64);
        int   io = __shfl_down(i1, off, 64);
        if (vo > v1 || (vo == v1 && io < i1)) { v1 = vo; i1 = io; }
      }
      v1 = __shfl(v1, 0, 64); i1 = __shfl(i1, 0, 64);
      float g2 = (lane == i1) ? -3.4e38f : g;
      float v2 = g2; int i2 = lane;
#pragma unroll
      for (int off = 32; off > 0; off >>= 1) {
        float vo = __shfl_down(v2, off, 64);
        int   io = __shfl_down(i2, off, 64);
        if (vo > v2 || (vo == v2 && io < i2)) { v2 = vo; i2 = io; }
      }
      if (lane == 0) {
        float ew  = __expf(v2 - v1);
        float inv = 1.f / (1.f + ew);
        ((float4*)out)[t] = make_float4((float)i1, inv, (float)i2, ew * inv);
      }
    }
    __syncthreads();
  }
}

extern "C" void kernel_launch(void* const* d_in, const int* in_sizes, int n_in,
                              void* d_out, int out_size, void* d_ws, size_t ws_size,
                              hipStream_t stream) {
  const float* th      = (const float*)d_in[0];  // [T, D]
  const float* rl      = (const float*)d_in[1];  // [T, E]
  const float* eg      = (const float*)d_in[2];  // [E, D]
  const float* alpha_p = (const float*)d_in[3];  // scalar
  float* out = (float*)d_out;                    // [T, 2, 2]

  short* egb = (short*)d_ws;                     // 1 MB bf16 hi/lo fragments
  int* cnt   = (int*)((char*)d_ws + (1 << 20));
  int* list  = cnt + 64;

  moe_precvt_kernel<<<256, 256, 0, stream>>>(eg, egb, cnt);
  moe_main_kernel<<<512, 256, 0, stream>>>(th, egb, rl, alpha_p, out, cnt, list);
  moe_fix_kernel<<<256, 256, 0, stream>>>(th, eg, rl, alpha_p, out, cnt, list);
}